// Round 6
// baseline (685.898 us; speedup 1.0000x reference)
//
#include <hip/hip_runtime.h>

#define NN 128
#define ME 32
#define DI 64
#define NZ 96
#define ROWD 130
#define MAXIT 5000

// ---- LDS layout (double offsets). R: [0, 16640). Total 20040 dbl = 160320 B <= 163840.
#define OFF_UN 16640
#define ROWB  (OFF_UN)           // [2][128] sweep row-k buffer (phase 2)
#define COLB  (OFF_UN + 256)     // [2][128] sweep col-k buffer (phase 2)
// loop window (4-slot exchange; w3 = matvec + obj wave; no ZEX buffers):
#define PPK   (OFF_UN)           // [2][4][64] packed (lo,hi) f32 partials in b64 slots
#define TVX   (OFF_UN + 512)     // [2][64] f64 per-lane tv terms (w3 internal)
#define TV16  (OFF_UN + 640)     // [2][16] f64 stage-A sums (w3 internal)
#define FLG   (OFF_UN + 672)     // [2] convergence flag (double 0/1)
#define YBUF  (OFF_UN)           // [128][12] Y block (stage 2; dead before loop)
#define KBUF  (OFF_UN + 1536)    // [12][96] K cols (stage 2; dead before loop)
#define CPART (OFF_UN + 1024)    // [2][128] (stage 3a)
#define VP    (OFF_UN + 1280)    // [4][128] (stage 3b)
#define BASEV (OFF_UN + 1792)    // [96] (persists through loop)
#define QBV   (OFF_UN + 1888)    // [96] (persists through loop)
#define FPART (OFF_UN + 1024)    // [2][128] (final)
#define RHSV  (OFF_UN + 1280)    // [128] (final)
#define XPART (OFF_UN + 1408)    // [2][128] (final)
#define CB    (OFF_UN + 2688)    // [128] c
#define QBUF  (OFF_UN + 2816)    // [128] q
#define V1    (OFF_UN + 2944)    // [128] Rc
#define V2    (OFF_UN + 3072)    // [128] Rq
#define HB    (OFF_UN + 3200)    // [64]
#define BB    (OFF_UN + 3264)    // [32]
#define CST   (OFF_UN + 3296)    // [8]: 0=u.c 1=q.u
#define ZBF   (OFF_UN + 3304)    // [96] z publish (final)
#define LDS_DBL (OFF_UN + 3400)  // 20040

typedef __attribute__((ext_vector_type(2))) float f32x2;

// f32 SGPR broadcast. CONTRACT: source computed by all lanes of the wave.
__device__ __forceinline__ float rlf(float v, int lane) {
  return __uint_as_float((unsigned)__builtin_amdgcn_readlane((int)__float_as_uint(v), lane));
}
__device__ __forceinline__ f32x2 fma2(f32x2 a, f32x2 b, f32x2 c) {
  return __builtin_elementwise_fma(a, b, c);   // v_pk_fma_f32
}

// matvec step: 2 pairs (4 cols) with broadcast lanes L0..L0+3 of ZS
#define MV2(PA, ZS, L0) {                                                  \
    f32x2 z0 = { rlf(ZS, L0), rlf(ZS, (L0)+1) };                           \
    A0 = fma2(Kp[PA], z0, A0); B0 = fma2(Kp2[PA], z0, B0);                 \
    f32x2 z1 = { rlf(ZS, (L0)+2), rlf(ZS, (L0)+3) };                       \
    A1 = fma2(Kp[(PA)+1], z1, A1); B1 = fma2(Kp2[(PA)+1], z1, B1); }

// copy KBUF cols [KBASE, KBASE+CNT) into local K pairs starting at local col LBASE
#define CPYRANGE(LBASE, KBASE, CNT)                                        \
  _Pragma("unroll") for (int j = 0; j < (CNT); ++j) {                      \
    const int lj = (LBASE) + j, kc = (KBASE) + j;                          \
    float va = (float)ldsd[KBUF + kc*NZ + l];                              \
    float vb = (float)ldsd[KBUF + kc*NZ + 64 + lm];                        \
    if ((lj & 1) == 0) { Kp[lj>>1].x = va; Kp2[lj>>1].x = vb; }            \
    else               { Kp[lj>>1].y = va; Kp2[lj>>1].y = vb; }            \
  }

__global__ __launch_bounds__(256, 1) void altdiff_kernel(
    const float* __restrict__ Qg, const float* __restrict__ qg,
    const float* __restrict__ Gg, const float* __restrict__ hg,
    const float* __restrict__ Ag, const float* __restrict__ bg,
    float* __restrict__ out)
{
  extern __shared__ double ldsd[];

  const int bidx = blockIdx.x;
  const int tid  = threadIdx.x;
  const int w    = tid >> 6;     // wave 0..3
  const int l    = tid & 63;     // lane
  const int lm   = l & 31;
  const int ia   = tid & 127;    // 128-split index
  const int hh   = tid >> 7;     // 0..1 (wave-uniform)

  const float* Qb = Qg + (size_t)bidx * NN * NN;
  const float* Ab = Ag + (size_t)bidx * ME * NN;
  const float* Gb = Gg + (size_t)bidx * DI * NN;
  const float* qb = qg + (size_t)bidx * NN;
  const float* hb = hg + (size_t)bidx * DI;
  const float* bv = bg + (size_t)bidx * ME;

  // stage h, b, q (f64)
  if (tid < DI) ldsd[HB + tid] = (double)hb[tid];
  else if (tid < DI + ME) ldsd[BB + tid - DI] = (double)bv[tid - DI];
  if (tid >= 128) ldsd[QBUF + tid - 128] = (double)qb[tid - 128];

  const int r = tid >> 4, c = tid & 15;   // 8x8 register tile at rows 8r.., cols 8c..
  double acc[8][8];                       // ALL indices compile-time constant (no scratch)

  // ---------------- Phase 1: M = Q + A^T A + G^T G (f64) -> registers ----------------
  {
    const float4* Q4 = (const float4*)Qb;
#pragma unroll
    for (int rr = 0; rr < 8; ++rr) {
      float4 q0 = Q4[((8*r+rr) << 5) + 2*c];
      float4 q1 = Q4[((8*r+rr) << 5) + 2*c + 1];
      acc[rr][0]=(double)q0.x; acc[rr][1]=(double)q0.y; acc[rr][2]=(double)q0.z; acc[rr][3]=(double)q0.w;
      acc[rr][4]=(double)q1.x; acc[rr][5]=(double)q1.y; acc[rr][6]=(double)q1.z; acc[rr][7]=(double)q1.w;
    }
    const float4* A4 = (const float4*)Ab;
    for (int m = 0; m < ME; ++m) {
      float4 u0 = A4[(m << 5) + 2*r], u1 = A4[(m << 5) + 2*r + 1];
      float4 v0 = A4[(m << 5) + 2*c], v1 = A4[(m << 5) + 2*c + 1];
      double uu[8] = {(double)u0.x,(double)u0.y,(double)u0.z,(double)u0.w,
                      (double)u1.x,(double)u1.y,(double)u1.z,(double)u1.w};
      double vv[8] = {(double)v0.x,(double)v0.y,(double)v0.z,(double)v0.w,
                      (double)v1.x,(double)v1.y,(double)v1.z,(double)v1.w};
#pragma unroll
      for (int rr = 0; rr < 8; ++rr)
#pragma unroll
        for (int cc = 0; cc < 8; ++cc)
          acc[rr][cc] = fma(uu[rr], vv[cc], acc[rr][cc]);
    }
    const float4* G4 = (const float4*)Gb;
    for (int d = 0; d < DI; ++d) {
      float4 u0 = G4[(d << 5) + 2*r], u1 = G4[(d << 5) + 2*r + 1];
      float4 v0 = G4[(d << 5) + 2*c], v1 = G4[(d << 5) + 2*c + 1];
      double uu[8] = {(double)u0.x,(double)u0.y,(double)u0.z,(double)u0.w,
                      (double)u1.x,(double)u1.y,(double)u1.z,(double)u1.w};
      double vv[8] = {(double)v0.x,(double)v0.y,(double)v0.z,(double)v0.w,
                      (double)v1.x,(double)v1.y,(double)v1.z,(double)v1.w};
#pragma unroll
      for (int rr = 0; rr < 8; ++rr)
#pragma unroll
        for (int cc = 0; cc < 8; ++cc)
          acc[rr][cc] = fma(uu[rr], vv[cc], acc[rr][cc]);
    }
  }

  // ---------------- Phase 2: register-tile sweep, 1 barrier/pivot, double-buffered ----------
  {
    if (r == 0) {
#pragma unroll
      for (int cc = 0; cc < 8; ++cc) ldsd[ROWB + 8*c + cc] = acc[0][cc];
    }
    if (c == 0) {
#pragma unroll
      for (int rr = 0; rr < 8; ++rr) ldsd[COLB + 8*r + rr] = acc[rr][0];
    }
    __syncthreads();
    for (int k = 0; k < NN; ++k) {
      const int pb = (k & 1) << 7;
      const int krt = k >> 3, kcl = k & 7;
      double rowk[8], colv[8];
#pragma unroll
      for (int cc = 0; cc < 8; ++cc) rowk[cc] = ldsd[ROWB + pb + 8*c + cc];
#pragma unroll
      for (int rr = 0; rr < 8; ++rr) colv[rr] = ldsd[COLB + pb + 8*r + rr];
      const double dkk  = ldsd[ROWB + pb + k];     // same-address broadcast
      const double rcpd = 1.0 / dkk;               // pivots >= 1 (M >= I)
      double rdv[8];
#pragma unroll
      for (int cc = 0; cc < 8; ++cc) rdv[cc] = rowk[cc] * rcpd;
      const bool pivR = (r == krt), pivC = (c == krt);
#pragma unroll
      for (int rr = 0; rr < 8; ++rr) {
        const double cv = colv[rr] * rcpd;
        const bool pr = pivR && (rr == kcl);
#pragma unroll
        for (int cc = 0; cc < 8; ++cc) {
          double gen = fma(-cv, rowk[cc], acc[rr][cc]);
          acc[rr][cc] = pr ? rdv[cc] : gen;
        }
      }
      if (pivC) {
#pragma unroll
        for (int cc = 0; cc < 8; ++cc) if (cc == kcl) {
#pragma unroll
          for (int rr = 0; rr < 8; ++rr) {
            const bool pr2 = pivR && (rr == kcl);
            acc[rr][cc] = pr2 ? -rcpd : colv[rr] * rcpd;
          }
        }
      }
      if (k < NN - 1) {
        const int pb2 = ((k + 1) & 1) << 7;
        const int krt2 = (k + 1) >> 3, kcl2 = (k + 1) & 7;
        if (r == krt2) {
#pragma unroll
          for (int rr = 0; rr < 8; ++rr) if (rr == kcl2) {
#pragma unroll
            for (int cc = 0; cc < 8; ++cc) ldsd[ROWB + pb2 + 8*c + cc] = acc[rr][cc];
          }
        }
        if (c == krt2) {
#pragma unroll
          for (int cc = 0; cc < 8; ++cc) if (cc == kcl2) {
#pragma unroll
            for (int rr = 0; rr < 8; ++rr) ldsd[COLB + pb2 + 8*r + rr] = acc[rr][cc];
          }
        }
      }
      __syncthreads();
    }
#pragma unroll
    for (int rr = 0; rr < 8; ++rr) {
      double2* dst = (double2*)(ldsd + (8*r+rr)*ROWD + 8*c);
#pragma unroll
      for (int t = 0; t < 4; ++t) dst[t] = make_double2(acc[rr][2*t], acc[rr][2*t+1]);
    }
  }
  __syncthreads();

  // ---------------- Stage 2: K = B (R B^T) in 8 blocks of 12 cols --------
  // Ownership: w0 cols 0..27, w1 cols 28..55, w2 cols 56..79, w3 cols 80..95.
  f32x2 Kp[14], Kp2[14];
  for (int blk = 0; blk < 8; ++blk) {
    {
      const float* gp[6];
#pragma unroll
      for (int jj = 0; jj < 6; ++jj) {
        int it = 12*blk + 6*hh + jj;
        gp[jj] = (it < DI) ? (Gb + it*NN) : (Ab + (it - DI)*NN);
      }
      double a2[6] = {0,0,0,0,0,0};
#pragma unroll 4
      for (int t = 0; t < NN; ++t) {
        double rv = ldsd[t*ROWD + ia];
#pragma unroll
        for (int jj = 0; jj < 6; ++jj)
          a2[jj] = fma(rv, (double)gp[jj][t], a2[jj]);
      }
      double2* yst = (double2*)(ldsd + YBUF + ia*12 + 6*hh);
#pragma unroll
      for (int p = 0; p < 3; ++p) yst[p] = make_double2(a2[2*p], a2[2*p+1]);
    }
    __syncthreads();
    {
      const int r2 = (ia < NZ) ? ia : 0;
      const float* brow = (r2 < DI) ? (Gb + r2*NN) : (Ab + (r2 - DI)*NN);
      double a2[6] = {0,0,0,0,0,0};
#pragma unroll 4
      for (int t = 0; t < NN; ++t) {
        double bvv = (double)brow[t];
        const double2* yr = (const double2*)(ldsd + YBUF + t*12 + 6*hh);
        double2 y0 = yr[0], y1 = yr[1], y2 = yr[2];
        a2[0] = fma(bvv, y0.x, a2[0]); a2[1] = fma(bvv, y0.y, a2[1]);
        a2[2] = fma(bvv, y1.x, a2[2]); a2[3] = fma(bvv, y1.y, a2[3]);
        a2[4] = fma(bvv, y2.x, a2[4]); a2[5] = fma(bvv, y2.y, a2[5]);
      }
      if (ia < NZ) {
#pragma unroll
        for (int jj = 0; jj < 6; ++jj) ldsd[KBUF + (6*hh + jj)*NZ + ia] = a2[jj];
      }
    }
    __syncthreads();
    // copy-out: constant indices per (wave, blk) arm
    if (w == 0) {
      if (blk == 0)      { CPYRANGE(0,  0, 12) }
      else if (blk == 1) { CPYRANGE(12, 0, 12) }
      else if (blk == 2) { CPYRANGE(24, 0, 4) }
    } else if (w == 1) {
      if (blk == 2)      { CPYRANGE(0,  4, 8) }
      else if (blk == 3) { CPYRANGE(8,  0, 12) }
      else if (blk == 4) { CPYRANGE(20, 0, 8) }
    } else if (w == 2) {
      if (blk == 4)      { CPYRANGE(0,  8, 4) }
      else if (blk == 5) { CPYRANGE(4,  0, 12) }
      else if (blk == 6) { CPYRANGE(16, 0, 8) }
    } else {
      if (blk == 6)      { CPYRANGE(0,  8, 4) }
      else if (blk == 7) { CPYRANGE(4,  0, 12) }
    }
    __syncthreads();
  }

  // ---------------- Stage 3a: c = q - G^T h - A^T b ----------------
  {
    double s = 0;
#pragma unroll 8
    for (int jc = 0; jc < 48; ++jc) {
      int j = 48*hh + jc;
      double coef = (j < DI) ? ldsd[HB + j] : ldsd[BB + j - DI];
      const float* src = (j < DI) ? (Gb + j*NN) : (Ab + (j - DI)*NN);
      s = fma(-(double)src[ia], coef, s);
    }
    ldsd[CPART + hh*128 + ia] = s;
  }
  __syncthreads();
  if (tid < NN) ldsd[CB + tid] = ldsd[QBUF + tid] + ldsd[CPART + tid] + ldsd[CPART + 128 + tid];
  __syncthreads();

  // ---------------- Stage 3b: v1 = R c, v2 = R q ----------------
  {
    double a = 0, b2 = 0;
#pragma unroll 4
    for (int tt = 0; tt < 64; ++tt) {
      int t = 64*hh + tt;
      double rv = ldsd[t*ROWD + ia];
      a  = fma(rv, ldsd[CB + t], a);
      b2 = fma(rv, ldsd[QBUF + t], b2);
    }
    ldsd[VP + hh*128 + ia] = a;
    ldsd[VP + 256 + hh*128 + ia] = b2;
  }
  __syncthreads();
  if (tid < NN) {
    ldsd[V1 + tid] = ldsd[VP + tid] + ldsd[VP + 128 + tid];
    ldsd[V2 + tid] = ldsd[VP + 256 + tid] + ldsd[VP + 384 + tid];
  }
  __syncthreads();

  // ---------------- Stage 3c: base = B v1, qB = B v2, scalars ----------------
  {
    const int r2 = (ia < NZ) ? ia : 0;
    const float* brow = (r2 < DI) ? (Gb + r2*NN) : (Ab + (r2 - DI)*NN);
    const int voff = hh ? V2 : V1;
    double s = 0;
#pragma unroll 4
    for (int t = 0; t < NN; ++t) s = fma((double)brow[t], ldsd[voff + t], s);
    if (ia < NZ) ldsd[(hh ? QBV : BASEV) + ia] = s;
  }
  if (w == 0) {
    double pc = ldsd[V1+l]*ldsd[CB+l]   + ldsd[V1+64+l]*ldsd[CB+64+l];
    double pq = ldsd[V1+l]*ldsd[QBUF+l] + ldsd[V1+64+l]*ldsd[QBUF+64+l];
#pragma unroll
    for (int off = 32; off >= 1; off >>= 1) { pc += __shfl_xor(pc, off); pq += __shfl_xor(pq, off); }
    if (l == 0) { ldsd[CST] = pc; ldsd[CST+1] = pq; }
  }
  __syncthreads();

  // ---------------- Loop setup ----------------
  // Cols: w0 lo[0:28), w1 lo[28:56), w2 lo[56:64)+hi[0:16), w3 hi[16:32).
  // All waves: read 4 slots, sum ((s0+s1)+(s2+s3)), f32 critical chain
  //   zflo = fabsf(hnbf - slo), zfhi = lbf + shi; f64 state updated off-path.
  // w3 additionally: z rings (f32), tv -> stageA -> stageB -> flag (timing verbatim).
  // ZEXL/ZEXH eliminated (w3 computes both chains in-register).
  const double baseA = ldsd[BASEV + l];
  const double baseB = ldsd[BASEV + 64 + lm];
  const double qvA   = ldsd[QBV + l];
  const double qvB   = ldsd[QBV + 64 + lm];
  const double hb2   = ldsd[HB + l] - baseA;       // h - baseA
  const double bb2   = baseB - ldsd[BB + lm];      // baseB - b
  const double S_uc  = ldsd[CST], S_qu = ldsd[CST + 1];
  double hnb = hb2, lb = bb2;                      // nu = 0, lam = 0 folded
  float hnbf = (float)hnb, lbf = (float)lb;        // f32 mirrors for the critical chain
  float zplo = 0.f, zphi = 0.f;                    // z computed last body (w3)
  float zAlo = 0.f, zAhi = 0.f, zBlo = 0.f, zBhi = 0.f, zClo = 0.f, zChi = 0.f;
  double res_prev = 1000.0, res_cur = -100.0;      // w3 obj recurrence

  // prologue: zero own P slot buf0; flags 0
  {
    *(float2*)&ldsd[PPK + w*64 + l] = make_float2(0.f, 0.f);
    if (tid == 0) { ldsd[FLG] = 0.0; ldsd[FLG + 1] = 0.0; }
  }

  // ---------------- ADMM loop: 1 barrier/body ----------------
  for (int it = 0; it < MAXIT + 3; ++it) {
    __syncthreads();
    const int buf = it & 1, nbuf = buf ^ 1;
    const int bprev = nbuf;                 // (it-1)&1
    const double fl = ldsd[FLG + bprev];    // flag stored body it-1 = decision for obj_{it-3}
    const float2* pb = (const float2*)(ldsd + PPK + buf*256);
    float2 p0 = pb[l], p1 = pb[64 + l], p2 = pb[128 + l], p3 = pb[192 + l];
    // w3 pipeline loads (parallel with partials)
    double a0 = 0, a1 = 0, a2 = 0, a3 = 0;
    double t1v[16];
    if (w == 3) {
      const int g = l & 15;
      const double* tq = ldsd + TVX + bprev*64;        // tv(it-1), stride-16 quartet
      a0 = tq[g]; a1 = tq[g + 16]; a2 = tq[g + 32]; a3 = tq[g + 48];
      const double2* tp = (const double2*)(ldsd + TV16 + bprev*16);  // sums of tv(it-2)
#pragma unroll
      for (int u = 0; u < 8; ++u) { double2 vv = tp[u]; t1v[2*u] = vv.x; t1v[2*u+1] = vv.y; }
    }
    // f32 critical chain (identical association on every wave -> duplicated state matches)
    float slo = (p0.x + p1.x) + (p2.x + p3.x);
    float tf   = hnbf - slo;
    float zflo = fabsf(tf);
    float shi = 0.f, zfhi = 0.f;
    if (w >= 2) {
      shi  = (p0.y + p1.y) + (p2.y + p3.y);
      zfhi = lbf + shi;
    }
    if (it >= 3 && fl != 0.0) break;
    // ring shifts (w3; zA = z entering THIS body)
    if (w == 3) { zClo = zBlo; zChi = zBhi; zBlo = zAlo; zBhi = zAhi; zAlo = zplo; zAhi = zphi; }
    if (it < MAXIT) {
      // off-path f64 state updates (scheduled under the burst)
      double t = hnb - (double)slo;
      hnb = hb2 + fmin(t, 0.0);              // = hb2 - relu(-t)
      hnbf = (float)hnb;
      if (w >= 2) {
        double lamn = lb + (double)shi;
        lb = lamn + bb2;
        lbf = (float)lb;
      }
      if (w == 3) { zplo = zflo; zphi = zfhi; }
      // matvec burst
      f32x2 A0 = {0.f, 0.f}, A1 = A0, B0 = A0, B1 = A0;
      if (w == 0) {
        MV2(0,  zflo, 0)  MV2(2,  zflo, 4)  MV2(4,  zflo, 8)  MV2(6,  zflo, 12)
        MV2(8,  zflo, 16) MV2(10, zflo, 20) MV2(12, zflo, 24)
      } else if (w == 1) {
        MV2(0,  zflo, 28) MV2(2,  zflo, 32) MV2(4,  zflo, 36) MV2(6,  zflo, 40)
        MV2(8,  zflo, 44) MV2(10, zflo, 48) MV2(12, zflo, 52)
      } else if (w == 2) {
        MV2(0,  zflo, 56) MV2(2,  zflo, 60)
        MV2(4,  zfhi, 0)  MV2(6,  zfhi, 4)  MV2(8,  zfhi, 8)  MV2(10, zfhi, 12)
      } else {
        MV2(0,  zfhi, 16) MV2(2,  zfhi, 20) MV2(4,  zfhi, 24) MV2(6,  zfhi, 28)
      }
      f32x2 As = A0 + A1, Bs = B0 + B1;     // v_pk_add_f32
      *(float2*)&ldsd[PPK + nbuf*256 + w*64 + l] = make_float2(As.x + As.y, Bs.x + Bs.y);
      // tv terms (w3, pipeline it): uses y(it) sums and zA = z(it-1)
      if (w == 3) {
        double yf  = (double)slo + baseA;
        double zAl = (double)zAlo;
        double tvl = fma(qvA, zAl, -0.5*(zAl*(baseA + yf) + yf*yf));
        double yfB = (double)shi + baseB;
        double zAh = (double)zAhi;
        double tvh = fma(qvB, zAh, -0.5*(zAh*(baseB + yfB) + yfB*yfB));
        ldsd[TVX + buf*64 + l] = tvl + ((l < 32) ? tvh : 0.0);
      }
    }
    if (w == 3) {
      // stage A (pipeline it-1)
      if (l < 16 && it >= 1 && it <= MAXIT)
        ldsd[TV16 + buf*16 + l] = (a0 + a1) + (a2 + a3);
      // stage B (pipeline it-2) -> flag
      if (it >= 2 && it <= MAXIT + 1) {
        double s1 = ((t1v[0] + t1v[1]) + (t1v[2] + t1v[3])) + ((t1v[4] + t1v[5]) + (t1v[6] + t1v[7]));
        double s2 = ((t1v[8] + t1v[9]) + (t1v[10] + t1v[11])) + ((t1v[12] + t1v[13]) + (t1v[14] + t1v[15]));
        double obj = (s1 + s2) - 0.5*S_uc + S_qu;
        res_prev = res_cur; res_cur = obj;
        if (l == 0)
          ldsd[FLG + buf] = (fabs(res_cur - res_prev) <= 1e-5 * fabs(res_prev)) ? 1.0 : 0.0;
      }
    }
  }

  // ---------------- Final: publish z (w3 rings: zC = top-of-stopping-body) -> LDS ------
  if (w == 3) {
    ldsd[ZBF + l] = (double)zClo;
    if (l < 32) ldsd[ZBF + 64 + l] = (double)zChi;
  }
  __syncthreads();
  // x = R (c + B^T z); z read via broadcast LDS loads
  {
    double s = 0;
#pragma unroll 8
    for (int jc = 0; jc < 48; ++jc) {
      int j = 48*hh + jc;
      double zj = ldsd[ZBF + j];
      const float* src = (j < DI) ? (Gb + j*NN) : (Ab + (j - DI)*NN);
      s = fma((double)src[ia], zj, s);
    }
    ldsd[FPART + hh*128 + ia] = s;
  }
  __syncthreads();
  if (tid < NN) ldsd[RHSV + tid] = ldsd[CB + tid] + ldsd[FPART + tid] + ldsd[FPART + 128 + tid];
  __syncthreads();
  {
    double s = 0;
#pragma unroll 4
    for (int tt = 0; tt < 64; ++tt) {
      int t = 64*hh + tt;
      s = fma(ldsd[t*ROWD + ia], ldsd[RHSV + t], s);   // R[t][ia] = R[ia][t]
    }
    ldsd[XPART + hh*128 + ia] = s;
  }
  __syncthreads();
  if (tid < NN)
    out[(size_t)bidx * NN + tid] = (float)(ldsd[XPART + tid] + ldsd[XPART + 128 + tid]);
}

extern "C" void kernel_launch(void* const* d_in, const int* in_sizes, int n_in,
                              void* d_out, int out_size, void* d_ws, size_t ws_size,
                              hipStream_t stream) {
  (void)in_sizes; (void)n_in; (void)out_size; (void)d_ws; (void)ws_size;
  const float* Q = (const float*)d_in[0];
  const float* q = (const float*)d_in[1];
  const float* G = (const float*)d_in[2];
  const float* h = (const float*)d_in[3];
  const float* A = (const float*)d_in[4];
  const float* b = (const float*)d_in[5];
  float* out = (float*)d_out;
  const size_t lds_bytes = (size_t)LDS_DBL * sizeof(double);  // 160320
  altdiff_kernel<<<dim3(64), dim3(256), lds_bytes, stream>>>(Q, q, G, h, A, b, out);
}

// Round 7
// 601.111 us; speedup vs baseline: 1.1411x; 1.1411x over previous
//
#include <hip/hip_runtime.h>

#define NN 128
#define ME 32
#define DI 64
#define NZ 96
#define ROWD 130
#define MAXIT 5000

// ---- LDS layout (double offsets). R: [0, 16640). Total 20040 dbl = 160320 B <= 163840.
#define OFF_UN 16640
#define ROWB  (OFF_UN)           // [2][128] sweep row-k buffer (phase 2)
#define COLB  (OFF_UN + 256)     // [2][128] sweep col-k buffer (phase 2)
// loop window (3-slot exchange + dedicated obj wave; f32 z publishes):
#define PPK   (OFF_UN)           // [2][3][64] packed (lo,hi) f32 partials in b64 slots
#define ZEXLF (2*(OFF_UN + 384)) // FLOAT idx: [2][64] f32 z_lo publish (w0 -> w3)
#define ZEXHF (2*(OFF_UN + 448)) // FLOAT idx: [2][32] f32 z_hi publish (w2 -> w3)
#define TVX   (OFF_UN + 480)     // [2][64] f64 per-lane tv terms (w3 internal)
#define TV16  (OFF_UN + 608)     // [2][16] f64 stage-A sums (w3 internal)
#define FLG   (OFF_UN + 640)     // [2] convergence flag (double 0/1)
#define YBUF  (OFF_UN)           // [128][12] Y block (stage 2; dead before loop)
#define KBUF  (OFF_UN + 1536)    // [12][96] K cols (stage 2; dead before loop)
#define CPART (OFF_UN + 1024)    // [2][128] (stage 3a)
#define VP    (OFF_UN + 1280)    // [4][128] (stage 3b)
#define BASEV (OFF_UN + 1792)    // [96] (persists through loop)
#define QBV   (OFF_UN + 1888)    // [96] (persists through loop)
#define FPART (OFF_UN + 1024)    // [2][128] (final)
#define RHSV  (OFF_UN + 1280)    // [128] (final)
#define XPART (OFF_UN + 1408)    // [2][128] (final)
#define CB    (OFF_UN + 2688)    // [128] c
#define QBUF  (OFF_UN + 2816)    // [128] q
#define V1    (OFF_UN + 2944)    // [128] Rc
#define V2    (OFF_UN + 3072)    // [128] Rq
#define HB    (OFF_UN + 3200)    // [64]
#define BB    (OFF_UN + 3264)    // [32]
#define CST   (OFF_UN + 3296)    // [8]: 0=u.c 1=q.u
#define ZBF   (OFF_UN + 3304)    // [96] z publish (final)
#define LDS_DBL (OFF_UN + 3400)  // 20040

typedef __attribute__((ext_vector_type(2))) float f32x2;

// f32 SGPR broadcast. CONTRACT: source computed by all lanes of the wave.
__device__ __forceinline__ float rlf(float v, int lane) {
  return __uint_as_float((unsigned)__builtin_amdgcn_readlane((int)__float_as_uint(v), lane));
}
__device__ __forceinline__ f32x2 fma2(f32x2 a, f32x2 b, f32x2 c) {
  return __builtin_elementwise_fma(a, b, c);   // v_pk_fma_f32
}

// matvec step: 2 pairs (4 cols) with broadcast lanes L0..L0+3 of ZS
#define MV2(PA, ZS, L0) {                                                  \
    f32x2 z0 = { rlf(ZS, L0), rlf(ZS, (L0)+1) };                           \
    A0 = fma2(Kp[PA], z0, A0); B0 = fma2(Kp2[PA], z0, B0);                 \
    f32x2 z1 = { rlf(ZS, (L0)+2), rlf(ZS, (L0)+3) };                       \
    A1 = fma2(Kp[(PA)+1], z1, A1); B1 = fma2(Kp2[(PA)+1], z1, B1); }

// copy KBUF cols [KBASE, KBASE+CNT) into local K pairs starting at local col LBASE
#define CPYRANGE(LBASE, KBASE, CNT)                                        \
  _Pragma("unroll") for (int j = 0; j < (CNT); ++j) {                      \
    const int lj = (LBASE) + j, kc = (KBASE) + j;                          \
    float va = (float)ldsd[KBUF + kc*NZ + l];                              \
    float vb = (float)ldsd[KBUF + kc*NZ + 64 + lm];                        \
    if ((lj & 1) == 0) { Kp[lj>>1].x = va; Kp2[lj>>1].x = vb; }            \
    else               { Kp[lj>>1].y = va; Kp2[lj>>1].y = vb; }            \
  }

__global__ __launch_bounds__(256, 1) void altdiff_kernel(
    const float* __restrict__ Qg, const float* __restrict__ qg,
    const float* __restrict__ Gg, const float* __restrict__ hg,
    const float* __restrict__ Ag, const float* __restrict__ bg,
    float* __restrict__ out)
{
  extern __shared__ double ldsd[];
  float* const ldsf = (float*)ldsd;

  const int bidx = blockIdx.x;
  const int tid  = threadIdx.x;
  const int w    = tid >> 6;     // wave 0..3
  const int l    = tid & 63;     // lane
  const int lm   = l & 31;
  const int ia   = tid & 127;    // 128-split index
  const int hh   = tid >> 7;     // 0..1 (wave-uniform)

  const float* Qb = Qg + (size_t)bidx * NN * NN;
  const float* Ab = Ag + (size_t)bidx * ME * NN;
  const float* Gb = Gg + (size_t)bidx * DI * NN;
  const float* qb = qg + (size_t)bidx * NN;
  const float* hb = hg + (size_t)bidx * DI;
  const float* bv = bg + (size_t)bidx * ME;

  // stage h, b, q (f64)
  if (tid < DI) ldsd[HB + tid] = (double)hb[tid];
  else if (tid < DI + ME) ldsd[BB + tid - DI] = (double)bv[tid - DI];
  if (tid >= 128) ldsd[QBUF + tid - 128] = (double)qb[tid - 128];

  const int r = tid >> 4, c = tid & 15;   // 8x8 register tile at rows 8r.., cols 8c..
  double acc[8][8];                       // ALL indices compile-time constant (no scratch)

  // ---------------- Phase 1: M = Q + A^T A + G^T G (f64) -> registers ----------------
  {
    const float4* Q4 = (const float4*)Qb;
#pragma unroll
    for (int rr = 0; rr < 8; ++rr) {
      float4 q0 = Q4[((8*r+rr) << 5) + 2*c];
      float4 q1 = Q4[((8*r+rr) << 5) + 2*c + 1];
      acc[rr][0]=(double)q0.x; acc[rr][1]=(double)q0.y; acc[rr][2]=(double)q0.z; acc[rr][3]=(double)q0.w;
      acc[rr][4]=(double)q1.x; acc[rr][5]=(double)q1.y; acc[rr][6]=(double)q1.z; acc[rr][7]=(double)q1.w;
    }
    const float4* A4 = (const float4*)Ab;
    for (int m = 0; m < ME; ++m) {
      float4 u0 = A4[(m << 5) + 2*r], u1 = A4[(m << 5) + 2*r + 1];
      float4 v0 = A4[(m << 5) + 2*c], v1 = A4[(m << 5) + 2*c + 1];
      double uu[8] = {(double)u0.x,(double)u0.y,(double)u0.z,(double)u0.w,
                      (double)u1.x,(double)u1.y,(double)u1.z,(double)u1.w};
      double vv[8] = {(double)v0.x,(double)v0.y,(double)v0.z,(double)v0.w,
                      (double)v1.x,(double)v1.y,(double)v1.z,(double)v1.w};
#pragma unroll
      for (int rr = 0; rr < 8; ++rr)
#pragma unroll
        for (int cc = 0; cc < 8; ++cc)
          acc[rr][cc] = fma(uu[rr], vv[cc], acc[rr][cc]);
    }
    const float4* G4 = (const float4*)Gb;
    for (int d = 0; d < DI; ++d) {
      float4 u0 = G4[(d << 5) + 2*r], u1 = G4[(d << 5) + 2*r + 1];
      float4 v0 = G4[(d << 5) + 2*c], v1 = G4[(d << 5) + 2*c + 1];
      double uu[8] = {(double)u0.x,(double)u0.y,(double)u0.z,(double)u0.w,
                      (double)u1.x,(double)u1.y,(double)u1.z,(double)u1.w};
      double vv[8] = {(double)v0.x,(double)v0.y,(double)v0.z,(double)v0.w,
                      (double)v1.x,(double)v1.y,(double)v1.z,(double)v1.w};
#pragma unroll
      for (int rr = 0; rr < 8; ++rr)
#pragma unroll
        for (int cc = 0; cc < 8; ++cc)
          acc[rr][cc] = fma(uu[rr], vv[cc], acc[rr][cc]);
    }
  }

  // ---------------- Phase 2: register-tile sweep, 1 barrier/pivot, double-buffered ----------
  {
    if (r == 0) {
#pragma unroll
      for (int cc = 0; cc < 8; ++cc) ldsd[ROWB + 8*c + cc] = acc[0][cc];
    }
    if (c == 0) {
#pragma unroll
      for (int rr = 0; rr < 8; ++rr) ldsd[COLB + 8*r + rr] = acc[rr][0];
    }
    __syncthreads();
    for (int k = 0; k < NN; ++k) {
      const int pb = (k & 1) << 7;
      const int krt = k >> 3, kcl = k & 7;
      double rowk[8], colv[8];
#pragma unroll
      for (int cc = 0; cc < 8; ++cc) rowk[cc] = ldsd[ROWB + pb + 8*c + cc];
#pragma unroll
      for (int rr = 0; rr < 8; ++rr) colv[rr] = ldsd[COLB + pb + 8*r + rr];
      const double dkk  = ldsd[ROWB + pb + k];     // same-address broadcast
      const double rcpd = 1.0 / dkk;               // pivots >= 1 (M >= I)
      double rdv[8];
#pragma unroll
      for (int cc = 0; cc < 8; ++cc) rdv[cc] = rowk[cc] * rcpd;
      const bool pivR = (r == krt), pivC = (c == krt);
#pragma unroll
      for (int rr = 0; rr < 8; ++rr) {
        const double cv = colv[rr] * rcpd;
        const bool pr = pivR && (rr == kcl);
#pragma unroll
        for (int cc = 0; cc < 8; ++cc) {
          double gen = fma(-cv, rowk[cc], acc[rr][cc]);
          acc[rr][cc] = pr ? rdv[cc] : gen;
        }
      }
      if (pivC) {
#pragma unroll
        for (int cc = 0; cc < 8; ++cc) if (cc == kcl) {
#pragma unroll
          for (int rr = 0; rr < 8; ++rr) {
            const bool pr2 = pivR && (rr == kcl);
            acc[rr][cc] = pr2 ? -rcpd : colv[rr] * rcpd;
          }
        }
      }
      if (k < NN - 1) {
        const int pb2 = ((k + 1) & 1) << 7;
        const int krt2 = (k + 1) >> 3, kcl2 = (k + 1) & 7;
        if (r == krt2) {
#pragma unroll
          for (int rr = 0; rr < 8; ++rr) if (rr == kcl2) {
#pragma unroll
            for (int cc = 0; cc < 8; ++cc) ldsd[ROWB + pb2 + 8*c + cc] = acc[rr][cc];
          }
        }
        if (c == krt2) {
#pragma unroll
          for (int cc = 0; cc < 8; ++cc) if (cc == kcl2) {
#pragma unroll
            for (int rr = 0; rr < 8; ++rr) ldsd[COLB + pb2 + 8*r + rr] = acc[rr][cc];
          }
        }
      }
      __syncthreads();
    }
#pragma unroll
    for (int rr = 0; rr < 8; ++rr) {
      double2* dst = (double2*)(ldsd + (8*r+rr)*ROWD + 8*c);
#pragma unroll
      for (int t = 0; t < 4; ++t) dst[t] = make_double2(acc[rr][2*t], acc[rr][2*t+1]);
    }
  }
  __syncthreads();

  // ---------------- Stage 2: K = B (R B^T) in 8 blocks of 12 cols --------
  // Ownership: w0 cols 0..31, w1 cols 32..63, w2 cols 64..95 (16 f32x2 pairs each).
  // Wave 3 holds nothing (objective wave).
  f32x2 Kp[16], Kp2[16];
  for (int blk = 0; blk < 8; ++blk) {
    {
      const float* gp[6];
#pragma unroll
      for (int jj = 0; jj < 6; ++jj) {
        int it = 12*blk + 6*hh + jj;
        gp[jj] = (it < DI) ? (Gb + it*NN) : (Ab + (it - DI)*NN);
      }
      double a2[6] = {0,0,0,0,0,0};
#pragma unroll 4
      for (int t = 0; t < NN; ++t) {
        double rv = ldsd[t*ROWD + ia];
#pragma unroll
        for (int jj = 0; jj < 6; ++jj)
          a2[jj] = fma(rv, (double)gp[jj][t], a2[jj]);
      }
      double2* yst = (double2*)(ldsd + YBUF + ia*12 + 6*hh);
#pragma unroll
      for (int p = 0; p < 3; ++p) yst[p] = make_double2(a2[2*p], a2[2*p+1]);
    }
    __syncthreads();
    {
      const int r2 = (ia < NZ) ? ia : 0;
      const float* brow = (r2 < DI) ? (Gb + r2*NN) : (Ab + (r2 - DI)*NN);
      double a2[6] = {0,0,0,0,0,0};
#pragma unroll 4
      for (int t = 0; t < NN; ++t) {
        double bvv = (double)brow[t];
        const double2* yr = (const double2*)(ldsd + YBUF + t*12 + 6*hh);
        double2 y0 = yr[0], y1 = yr[1], y2 = yr[2];
        a2[0] = fma(bvv, y0.x, a2[0]); a2[1] = fma(bvv, y0.y, a2[1]);
        a2[2] = fma(bvv, y1.x, a2[2]); a2[3] = fma(bvv, y1.y, a2[3]);
        a2[4] = fma(bvv, y2.x, a2[4]); a2[5] = fma(bvv, y2.y, a2[5]);
      }
      if (ia < NZ) {
#pragma unroll
        for (int jj = 0; jj < 6; ++jj) ldsd[KBUF + (6*hh + jj)*NZ + ia] = a2[jj];
      }
    }
    __syncthreads();
    // copy-out: constant indices per (wave, blk) arm
    if (w == 0) {
      if (blk == 0)      { CPYRANGE(0,  0, 12) }
      else if (blk == 1) { CPYRANGE(12, 0, 12) }
      else if (blk == 2) { CPYRANGE(24, 0, 8) }
    } else if (w == 1) {
      if (blk == 2)      { CPYRANGE(0,  8, 4) }
      else if (blk == 3) { CPYRANGE(4,  0, 12) }
      else if (blk == 4) { CPYRANGE(16, 0, 12) }
      else if (blk == 5) { CPYRANGE(28, 0, 4) }
    } else if (w == 2) {
      if (blk == 5)      { CPYRANGE(0,  4, 8) }
      else if (blk == 6) { CPYRANGE(8,  0, 12) }
      else if (blk == 7) { CPYRANGE(20, 0, 12) }
    }
    __syncthreads();
  }

  // ---------------- Stage 3a: c = q - G^T h - A^T b ----------------
  {
    double s = 0;
#pragma unroll 8
    for (int jc = 0; jc < 48; ++jc) {
      int j = 48*hh + jc;
      double coef = (j < DI) ? ldsd[HB + j] : ldsd[BB + j - DI];
      const float* src = (j < DI) ? (Gb + j*NN) : (Ab + (j - DI)*NN);
      s = fma(-(double)src[ia], coef, s);
    }
    ldsd[CPART + hh*128 + ia] = s;
  }
  __syncthreads();
  if (tid < NN) ldsd[CB + tid] = ldsd[QBUF + tid] + ldsd[CPART + tid] + ldsd[CPART + 128 + tid];
  __syncthreads();

  // ---------------- Stage 3b: v1 = R c, v2 = R q ----------------
  {
    double a = 0, b2 = 0;
#pragma unroll 4
    for (int tt = 0; tt < 64; ++tt) {
      int t = 64*hh + tt;
      double rv = ldsd[t*ROWD + ia];
      a  = fma(rv, ldsd[CB + t], a);
      b2 = fma(rv, ldsd[QBUF + t], b2);
    }
    ldsd[VP + hh*128 + ia] = a;
    ldsd[VP + 256 + hh*128 + ia] = b2;
  }
  __syncthreads();
  if (tid < NN) {
    ldsd[V1 + tid] = ldsd[VP + tid] + ldsd[VP + 128 + tid];
    ldsd[V2 + tid] = ldsd[VP + 256 + tid] + ldsd[VP + 384 + tid];
  }
  __syncthreads();

  // ---------------- Stage 3c: base = B v1, qB = B v2, scalars ----------------
  {
    const int r2 = (ia < NZ) ? ia : 0;
    const float* brow = (r2 < DI) ? (Gb + r2*NN) : (Ab + (r2 - DI)*NN);
    const int voff = hh ? V2 : V1;
    double s = 0;
#pragma unroll 4
    for (int t = 0; t < NN; ++t) s = fma((double)brow[t], ldsd[voff + t], s);
    if (ia < NZ) ldsd[(hh ? QBV : BASEV) + ia] = s;
  }
  if (w == 0) {
    double pc = ldsd[V1+l]*ldsd[CB+l]   + ldsd[V1+64+l]*ldsd[CB+64+l];
    double pq = ldsd[V1+l]*ldsd[QBUF+l] + ldsd[V1+64+l]*ldsd[QBUF+64+l];
#pragma unroll
    for (int off = 32; off >= 1; off >>= 1) { pc += __shfl_xor(pc, off); pq += __shfl_xor(pq, off); }
    if (l == 0) { ldsd[CST] = pc; ldsd[CST+1] = pq; }
  }
  __syncthreads();

  // ---------------- Loop setup (r5 structure + f32 critical chain) ----------------
  // w0: cols 0..31 (z_lo) + f32 z_lo publish.   w1: cols 32..63 (z_lo, dup state).
  // w2: cols 64..95 (z_hi) + f32 z_hi publish.  w3: obj pipeline + z rings (f32).
  // Critical chain is f32 (hnbf/lbf mirrors); exact f64 state updated off-path,
  // bit-identical recurrence to r5 (t = hnb - (double)slo; hnb = hb2 + fmin(t,0)).
  const double baseA = ldsd[BASEV + l];
  const double baseB = ldsd[BASEV + 64 + lm];
  const double qvA   = ldsd[QBV + l];
  const double qvB   = ldsd[QBV + 64 + lm];
  const double hb2   = ldsd[HB + l] - baseA;       // h - baseA
  const double bb2   = baseB - ldsd[BB + lm];      // baseB - b
  const double S_uc  = ldsd[CST], S_qu = ldsd[CST + 1];
  double hnb = hb2, lb = bb2;                      // nu = 0, lam = 0 folded
  float hnbf = (float)hnb, lbf = (float)lb;        // f32 mirrors (critical chain)
  float zAf_lo = 0.f, zAf_hi = 0.f, zBf_lo = 0.f, zBf_hi = 0.f, zCf_lo = 0.f, zCf_hi = 0.f;
  double res_prev = 1000.0, res_cur = -100.0;      // w3 obj recurrence
  float2 own = make_float2(0.f, 0.f);              // own partial (w0/w1/w2), reg-resident

  // prologue: zero P buf0 slots; z(-1)=0 into ZEX buf1; flags 0
  {
    if (w < 3) *(float2*)&ldsd[PPK + w*64 + l] = make_float2(0.f, 0.f);
    if (w == 0) ldsf[ZEXLF + 64 + l] = 0.f;
    if (w == 2 && l < 32) ldsf[ZEXHF + 32 + l] = 0.f;
    if (tid == 0) { ldsd[FLG] = 0.0; ldsd[FLG + 1] = 0.0; }
  }

  // ---------------- ADMM loop: 1 barrier/body ----------------
  for (int it = 0; it < MAXIT + 3; ++it) {
    __syncthreads();
    const int buf = it & 1, nbuf = buf ^ 1;
    const int bprev = nbuf;                 // (it-1)&1
    const double fl = ldsd[FLG + bprev];    // flag stored body it-1 = decision for obj_{it-3}
    const float2* pb = (const float2*)(ldsd + PPK + buf*192);

    if (w == 0) {
      float2 s1v = pb[64 + l], s2v = pb[128 + l];
      float slo = (own.x + s1v.x) + s2v.x;            // (s0+s1)+s2
      float zflo = fabsf(hnbf - slo);                 // f32 critical chain
      if (it >= 3 && fl != 0.0) break;
      if (it < MAXIT) {
        ldsf[ZEXLF + buf*64 + l] = zflo;              // f32 publish
        // off-path exact f64 state (r5 recurrence, bit-identical)
        double t = hnb - (double)slo;
        hnb = hb2 + fmin(t, 0.0);                     // = hb2 - relu(-t)
        hnbf = (float)hnb;
        f32x2 A0 = {0.f, 0.f}, A1 = A0, B0 = A0, B1 = A0;
        MV2(0,  zflo, 0)  MV2(2,  zflo, 4)  MV2(4,  zflo, 8)  MV2(6,  zflo, 12)
        MV2(8,  zflo, 16) MV2(10, zflo, 20) MV2(12, zflo, 24) MV2(14, zflo, 28)
        f32x2 As = A0 + A1, Bs = B0 + B1;
        float2 np = make_float2(As.x + As.y, Bs.x + Bs.y);
        *(float2*)&ldsd[PPK + nbuf*192 + l] = np;
        own = np;
      }
    } else if (w == 1) {
      float2 s0v = pb[l], s2v = pb[128 + l];
      float slo = (s0v.x + own.x) + s2v.x;            // (s0+s1)+s2
      float zflo = fabsf(hnbf - slo);
      if (it >= 3 && fl != 0.0) break;
      if (it < MAXIT) {
        double t = hnb - (double)slo;
        hnb = hb2 + fmin(t, 0.0);
        hnbf = (float)hnb;
        f32x2 A0 = {0.f, 0.f}, A1 = A0, B0 = A0, B1 = A0;
        MV2(0,  zflo, 32) MV2(2,  zflo, 36) MV2(4,  zflo, 40) MV2(6,  zflo, 44)
        MV2(8,  zflo, 48) MV2(10, zflo, 52) MV2(12, zflo, 56) MV2(14, zflo, 60)
        f32x2 As = A0 + A1, Bs = B0 + B1;
        float2 np = make_float2(As.x + As.y, Bs.x + Bs.y);
        *(float2*)&ldsd[PPK + nbuf*192 + 64 + l] = np;
        own = np;
      }
    } else if (w == 2) {
      float2 s0v = pb[l], s1v = pb[64 + l];
      float shi = (s0v.y + s1v.y) + own.y;            // (s0+s1)+s2
      float zfhi = lbf + shi;                         // f32 critical chain
      if (it >= 3 && fl != 0.0) break;
      if (it < MAXIT) {
        if (l < 32) ldsf[ZEXHF + buf*32 + l] = zfhi;  // f32 publish
        // off-path exact f64 state
        double lamn = lb + (double)shi;
        lb = lamn + bb2;
        lbf = (float)lb;
        f32x2 A0 = {0.f, 0.f}, A1 = A0, B0 = A0, B1 = A0;
        MV2(0,  zfhi, 0)  MV2(2,  zfhi, 4)  MV2(4,  zfhi, 8)  MV2(6,  zfhi, 12)
        MV2(8,  zfhi, 16) MV2(10, zfhi, 20) MV2(12, zfhi, 24) MV2(14, zfhi, 28)
        f32x2 As = A0 + A1, Bs = B0 + B1;
        float2 np = make_float2(As.x + As.y, Bs.x + Bs.y);
        *(float2*)&ldsd[PPK + nbuf*192 + 128 + l] = np;
        own = np;
      }
    } else {
      // ---------------- w3: objective pipeline + z rings ----------------
      float2 v0 = pb[l], v1 = pb[64 + l], v2 = pb[128 + l];
      const float ztl = ldsf[ZEXLF + bprev*64 + l];    // z_top(it) = z(it-1)
      const float zth = ldsf[ZEXHF + bprev*32 + lm];
      const int g = l & 15;
      const double* tq = ldsd + TVX + bprev*64;        // tv(it-1), stride-16 quartet
      double a0 = tq[g], a1 = tq[g + 16], a2 = tq[g + 32], a3 = tq[g + 48];
      double t1v[16];
      const double2* tp = (const double2*)(ldsd + TV16 + bprev*16);  // sums of tv(it-2)
#pragma unroll
      for (int u = 0; u < 8; ++u) { double2 vv = tp[u]; t1v[2*u] = vv.x; t1v[2*u+1] = vv.y; }
      if (it >= 3 && fl != 0.0) break;
      // ring shift (zA = z entering THIS body)
      zCf_lo = zBf_lo; zCf_hi = zBf_hi; zBf_lo = zAf_lo; zBf_hi = zAf_hi;
      zAf_lo = ztl;    zAf_hi = zth;
      // stage tv (pipeline it)
      if (it < MAXIT) {
        float slo_f = (v0.x + v1.x) + v2.x;
        float shi_f = (v0.y + v1.y) + v2.y;
        double zAl = (double)zAf_lo;
        double yf  = (double)slo_f + baseA;
        double tvl = fma(qvA, zAl, -0.5*(zAl*(baseA + yf) + yf*yf));
        double zAh = (double)zAf_hi;
        double yfB = (double)shi_f + baseB;
        double tvh = fma(qvB, zAh, -0.5*(zAh*(baseB + yfB) + yfB*yfB));
        ldsd[TVX + buf*64 + l] = tvl + ((l < 32) ? tvh : 0.0);
      }
      // stage A (pipeline it-1)
      if (l < 16 && it >= 1 && it <= MAXIT)
        ldsd[TV16 + buf*16 + l] = (a0 + a1) + (a2 + a3);
      // stage B (pipeline it-2) -> flag
      if (it >= 2 && it <= MAXIT + 1) {
        double s1 = ((t1v[0] + t1v[1]) + (t1v[2] + t1v[3])) + ((t1v[4] + t1v[5]) + (t1v[6] + t1v[7]));
        double s2 = ((t1v[8] + t1v[9]) + (t1v[10] + t1v[11])) + ((t1v[12] + t1v[13]) + (t1v[14] + t1v[15]));
        double obj = (s1 + s2) - 0.5*S_uc + S_qu;
        res_prev = res_cur; res_cur = obj;
        if (l == 0)
          ldsd[FLG + buf] = (fabs(res_cur - res_prev) <= 1e-5 * fabs(res_prev)) ? 1.0 : 0.0;
      }
    }
  }

  // ---------------- Final: publish z (w3 rings: zC = top-of-stopping-body) -> LDS ------
  if (w == 3) {
    ldsd[ZBF + l] = (double)zCf_lo;
    if (l < 32) ldsd[ZBF + 64 + l] = (double)zCf_hi;
  }
  __syncthreads();
  // x = R (c + B^T z); z read via broadcast LDS loads
  {
    double s = 0;
#pragma unroll 8
    for (int jc = 0; jc < 48; ++jc) {
      int j = 48*hh + jc;
      double zj = ldsd[ZBF + j];
      const float* src = (j < DI) ? (Gb + j*NN) : (Ab + (j - DI)*NN);
      s = fma((double)src[ia], zj, s);
    }
    ldsd[FPART + hh*128 + ia] = s;
  }
  __syncthreads();
  if (tid < NN) ldsd[RHSV + tid] = ldsd[CB + tid] + ldsd[FPART + tid] + ldsd[FPART + 128 + tid];
  __syncthreads();
  {
    double s = 0;
#pragma unroll 4
    for (int tt = 0; tt < 64; ++tt) {
      int t = 64*hh + tt;
      s = fma(ldsd[t*ROWD + ia], ldsd[RHSV + t], s);   // R[t][ia] = R[ia][t]
    }
    ldsd[XPART + hh*128 + ia] = s;
  }
  __syncthreads();
  if (tid < NN)
    out[(size_t)bidx * NN + tid] = (float)(ldsd[XPART + tid] + ldsd[XPART + 128 + tid]);
}

extern "C" void kernel_launch(void* const* d_in, const int* in_sizes, int n_in,
                              void* d_out, int out_size, void* d_ws, size_t ws_size,
                              hipStream_t stream) {
  (void)in_sizes; (void)n_in; (void)out_size; (void)d_ws; (void)ws_size;
  const float* Q = (const float*)d_in[0];
  const float* q = (const float*)d_in[1];
  const float* G = (const float*)d_in[2];
  const float* h = (const float*)d_in[3];
  const float* A = (const float*)d_in[4];
  const float* b = (const float*)d_in[5];
  float* out = (float*)d_out;
  const size_t lds_bytes = (size_t)LDS_DBL * sizeof(double);  // 160320
  altdiff_kernel<<<dim3(64), dim3(256), lds_bytes, stream>>>(Q, q, G, h, A, b, out);
}